// Round 4
// baseline (399.919 us; speedup 1.0000x reference)
//
#include <hip/hip_runtime.h>
#include <stdint.h>

#define BB 8
#define CIN 256
#define NSP 16384      // H*W
#define HID 128

typedef __bf16 bfrag __attribute__((ext_vector_type(8)));
typedef float  f32x4 __attribute__((ext_vector_type(4)));
typedef unsigned short us8 __attribute__((ext_vector_type(8)));

__device__ __forceinline__ unsigned short f2bf(float f) {
  union { float f; unsigned int u; } v; v.f = f;
  unsigned int u = v.u;
  return (unsigned short)((u + 0x7FFFu + ((u >> 16) & 1u)) >> 16);  // RNE
}

__device__ __forceinline__ bfrag us8_to_bfrag(us8 u) {
  union { us8 u; bfrag b; } c; c.u = u; return c.b;
}

// async global->LDS, 16B per lane (lane-linear dest).
__device__ __forceinline__ void gload_lds16(const unsigned short* g, unsigned short* l) {
  __builtin_amdgcn_global_load_lds((const __attribute__((address_space(1))) void*)g,
                                   (__attribute__((address_space(3))) void*)l, 16, 0, 0);
}

#define FENCE() asm volatile("" ::: "memory")

// ---------------- prep: wkvb = bf16(w_qkv rows 128..383); zero ctxu+sums ----------------
__global__ __launch_bounds__(256) void la_prep(const float* __restrict__ w_qkv,
                                               unsigned short* __restrict__ wkvb,
                                               float* __restrict__ zbase) {
  const int blk = blockIdx.x;
  const int t = threadIdx.x;
  if (blk < 64) {
    const int off = (blk * 256 + t) * 4;   // 0..65532
    const float4 wv4 = *(const float4*)(w_qkv + (size_t)128 * CIN + off);
    ushort4 p;
    p.x = f2bf(wv4.x); p.y = f2bf(wv4.y); p.z = f2bf(wv4.z); p.w = f2bf(wv4.w);
    *(ushort4*)(wkvb + off) = p;
  } else {
    // zero ctxu (32768 f) + sums (1024 f) contiguous = 8448 float4
    for (int i = t; i < 8448; i += 256) {
      float4 z = {0.f, 0.f, 0.f, 0.f};
      *(float4*)(zbase + i * 4) = z;
    }
  }
}

// ---------------- pass 1: transpose x tile -> LDS (+ write xT), swapped-operand k/v GEMM,
//                  register-local ctx MFMA, LDS combine -> atomic ctxu/sums ----------------
// Block: 128-n tile of one batch, 512 threads = 8 waves.
// GEMM: D[n][kv] = xT_tile . wkvb^T : M=128(n), N=256(kv: k 0..127, v 128..255), K=256(c).
// Wave wv owns n-rows [wv*16, wv*16+16): acc[16] col-frags (64 VGPR).
// C/D layout: lane(l15,q) holds D[n=q*4+rg][kv=cf*16+l15] -> exp(k)/v accs ARE the
// A/B fragments (k-slots 0..3, rest zero) of the ctx MFMA over this wave's 16 n.
__global__ __launch_bounds__(512, 4) void la_pass1(const float* __restrict__ x,
                                                   const unsigned short* __restrict__ wkvb,
                                                   unsigned short* __restrict__ xT,
                                                   float* __restrict__ ctxu,
                                                   float* __restrict__ sums) {
  __shared__ __align__(16) union {
    struct { unsigned short Xb[2][128][40]; } g;         // 20480 B staging (dbuf)
    struct { float Pc[4][4096]; float Sw[8][128]; } e;   // 69632 B epilogue
  } sh;
  const int chunk = blockIdx.x;
  const int n0 = chunk * 128;
  const int b = blockIdx.y;
  const int t = threadIdx.x;
  const int lane = t & 63, wv = t >> 6;
  const int l15 = lane & 15, q = lane >> 4;
  const int cl = t & 31;                 // c within 32-chunk (staging)
  const int n16 = (t >> 5) * 8;          // 8 n-rows per thread (staging)
  const float* xp = x + (size_t)b * CIN * NSP + n0;
  unsigned short* xTb = xT + ((size_t)b * NSP + n0) * CIN;
  f32x4 acc[16];
#pragma unroll
  for (int i = 0; i < 16; ++i) acc[i] = 0.0f;

#define STOREX(B, A0, A1) do {                      \
    sh.g.Xb[B][n16 + 0][cl] = f2bf((A0).x);         \
    sh.g.Xb[B][n16 + 1][cl] = f2bf((A0).y);         \
    sh.g.Xb[B][n16 + 2][cl] = f2bf((A0).z);         \
    sh.g.Xb[B][n16 + 3][cl] = f2bf((A0).w);         \
    sh.g.Xb[B][n16 + 4][cl] = f2bf((A1).x);         \
    sh.g.Xb[B][n16 + 5][cl] = f2bf((A1).y);         \
    sh.g.Xb[B][n16 + 6][cl] = f2bf((A1).z);         \
    sh.g.Xb[B][n16 + 7][cl] = f2bf((A1).w);         \
  } while (0)

  float4 xa0, xa1;
  {  // prologue: load kc=0, stage buf0, load kc=1
    const float* xr = xp + (size_t)cl * NSP + n16;
    xa0 = *(const float4*)xr;
    xa1 = *(const float4*)(xr + 4);
  }
  STOREX(0, xa0, xa1);
  {
    const float* xr = xp + (size_t)(32 + cl) * NSP + n16;
    xa0 = *(const float4*)xr;
    xa1 = *(const float4*)(xr + 4);
  }
  __syncthreads();

#pragma unroll
  for (int kc = 0; kc < 8; ++kc) {
    const int buf = kc & 1;
    if (kc < 7) {
      STOREX(buf ^ 1, xa0, xa1);
      if (kc < 6) {
        const float* xr = xp + (size_t)((kc + 2) * 32 + cl) * NSP + n16;
        xa0 = *(const float4*)xr;
        xa1 = *(const float4*)(xr + 4);
      }
    }
    // xT writeback: thread t reads 16B of the transposed tile, stores to global
    {
      const int rr = t >> 2, cc8 = (t & 3) * 8;
      us8 wbv = *(const us8*)&sh.g.Xb[buf][rr][cc8];
      *(us8*)(xTb + (size_t)rr * CIN + kc * 32 + cc8) = wbv;
    }
    // A-frag: this wave's 16 n-rows, c-run q*8 (single ds_read_b128)
    bfrag af = *(const bfrag*)&sh.g.Xb[buf][wv * 16 + l15][q * 8];
    // B-frags: wkvb direct (L1-resident; identical across waves -> broadcast)
    const unsigned short* wbp = wkvb + (size_t)l15 * CIN + kc * 32 + q * 8;
#pragma unroll
    for (int cf = 0; cf < 16; ++cf) {
      bfrag bv = *(const bfrag*)(wbp + (size_t)cf * 16 * CIN);
      acc[cf] = __builtin_amdgcn_mfma_f32_16x16x32_bf16(af, bv, acc[cf], 0, 0, 0);
    }
    __syncthreads();
  }
#undef STOREX

  // ---- exp in place on k cols (cf 0..7) ----
#pragma unroll
  for (int cf = 0; cf < 8; ++cf)
#pragma unroll
    for (int rg = 0; rg < 4; ++rg) acc[cf][rg] = __expf(acc[cf][rg]);

  // ---- sums: per-wave 16-n partial per d, staged to Sw ----
#pragma unroll
  for (int cf = 0; cf < 8; ++cf) {
    float s = acc[cf][0] + acc[cf][1] + acc[cf][2] + acc[cf][3];
    s += __shfl_xor(s, 16);
    s += __shfl_xor(s, 32);
    if (q == 0) sh.e.Sw[wv][cf * 16 + l15] = s;
  }

  // ---- ctx: 16x16x32 MFMA with k-slots 4..7 zeroed (K=16 effective over this wave's n) ----
  f32x4 ct[16];
#pragma unroll
  for (int i = 0; i < 16; ++i) ct[i] = 0.0f;
#pragma unroll
  for (int hh = 0; hh < 2; ++hh) {       // heads {0,1} then {2,3}
    bfrag kf[4], vf[4];
#pragma unroll
    for (int i = 0; i < 4; ++i) {
      const int cf = hh * 4 + i;
      us8 kt = {0, 0, 0, 0, 0, 0, 0, 0};
      us8 vt = {0, 0, 0, 0, 0, 0, 0, 0};
      kt[0] = f2bf(acc[cf][0]); kt[1] = f2bf(acc[cf][1]);
      kt[2] = f2bf(acc[cf][2]); kt[3] = f2bf(acc[cf][3]);
      vt[0] = f2bf(acc[8 + cf][0]); vt[1] = f2bf(acc[8 + cf][1]);
      vt[2] = f2bf(acc[8 + cf][2]); vt[3] = f2bf(acc[8 + cf][3]);
      kf[i] = us8_to_bfrag(kt);
      vf[i] = us8_to_bfrag(vt);
    }
#pragma unroll
    for (int hl = 0; hl < 2; ++hl)
#pragma unroll
      for (int dt = 0; dt < 2; ++dt)
#pragma unroll
        for (int et = 0; et < 2; ++et) {
          const int tix = (hh * 2 + hl) * 4 + dt * 2 + et;
          ct[tix] = __builtin_amdgcn_mfma_f32_16x16x32_bf16(kf[hl * 2 + dt], vf[hl * 2 + et],
                                                            ct[tix], 0, 0, 0);
        }
  }

  // ---- combine 8 wave-partials: waves 0-3 write Pc slots, 4-7 add; XOR-swizzled [e][d] ----
  {
    const int slot = wv & 3;
    float* pcs = sh.e.Pc[slot];
    if (wv < 4) {
#pragma unroll
      for (int h = 0; h < 4; ++h)
#pragma unroll
        for (int dt = 0; dt < 2; ++dt)
#pragma unroll
          for (int et = 0; et < 2; ++et) {
            const int e = et * 16 + l15;
            const int sd = (dt * 16 + q * 4) ^ ((e & 7) << 2);
            *(f32x4*)&pcs[h * 1024 + e * 32 + sd] = ct[h * 4 + dt * 2 + et];
          }
    }
    __syncthreads();
    if (wv >= 4) {
#pragma unroll
      for (int h = 0; h < 4; ++h)
#pragma unroll
        for (int dt = 0; dt < 2; ++dt)
#pragma unroll
          for (int et = 0; et < 2; ++et) {
            const int e = et * 16 + l15;
            const int sd = (dt * 16 + q * 4) ^ ((e & 7) << 2);
            f32x4 o = *(const f32x4*)&pcs[h * 1024 + e * 32 + sd];
            o += ct[h * 4 + dt * 2 + et];
            *(f32x4*)&pcs[h * 1024 + e * 32 + sd] = o;
          }
    }
    __syncthreads();
  }

  // ---- finalize: sums + ctx -> global atomics ----
  if (t < 128) {
    float s8 = 0.f;
#pragma unroll
    for (int w = 0; w < 8; ++w) s8 += sh.e.Sw[w][t];
    atomicAdd(&sums[b * 128 + t], s8);
  }
  {
    float* cub = ctxu + (size_t)b * 4096;
    f32x4 v0 = {0.f, 0.f, 0.f, 0.f}, v1 = {0.f, 0.f, 0.f, 0.f};
#pragma unroll
    for (int s = 0; s < 4; ++s) {
      v0 += *(const f32x4*)&sh.e.Pc[s][t * 4];
      v1 += *(const f32x4*)&sh.e.Pc[s][2048 + t * 4];
    }
#pragma unroll
    for (int j = 0; j < 4; ++j) {
      int pos = t * 4 + j;
      int h = pos >> 10, e = (pos >> 5) & 31, sd = pos & 31;
      int d = sd ^ ((e & 7) << 2);
      atomicAdd(&cub[(h * 32 + d) * 32 + e], v0[j]);
      pos = 2048 + t * 4 + j;
      h = pos >> 10; e = (pos >> 5) & 31; sd = pos & 31;
      d = sd ^ ((e & 7) << 2);
      atomicAdd(&cub[(h * 32 + d) * 32 + e], v1[j]);
    }
  }
}

// ---------------- mid: weff row (in LDS) -> wcomb row, fused ----------------
__global__ __launch_bounds__(256) void la_mid(const float* __restrict__ w_out,
                                              const float* __restrict__ ctxu,
                                              const float* __restrict__ sums,
                                              const float* __restrict__ w_qkv,
                                              unsigned short* __restrict__ wcomb) {
  __shared__ float wrow[128];
  const int o = blockIdx.x;
  const int b = blockIdx.y;
  const int t = threadIdx.x;
  if (t < 128) {
    const int h = t >> 5, d = t & 31;
    const float* wr = w_out + (size_t)o * HID + h * 32;
    const float* cr = ctxu + ((size_t)(b * 4 + h) * 32 + d) * 32;
    float s = 0.f;
#pragma unroll 8
    for (int e = 0; e < 32; ++e) s += wr[e] * cr[e];
    wrow[t] = s * (1.0f / sums[b * 128 + t]);
  }
  __syncthreads();
  float s = 0.f;
#pragma unroll 8
  for (int hd = 0; hd < 128; ++hd) s += wrow[hd] * w_qkv[(size_t)hd * CIN + t];
  wcomb[((size_t)b * 256 + o) * 256 + t] = f2bf(s);
}

// ---------------- out[b][o][n] = sum_c Wcomb[b][o][c] * xT + b_out[o] ----------------
// (verbatim round-3 structure: gload_lds staging from xT, counted vmcnt pipeline)
__global__ __launch_bounds__(512, 4) void la_out(const unsigned short* __restrict__ wcomb,
                                                 const unsigned short* __restrict__ xT,
                                                 const float* __restrict__ b_out,
                                                 float* __restrict__ out) {
  __shared__ __align__(16) unsigned short Sx[4][4096];
  const int n0 = blockIdx.x * 128;
  const int b = blockIdx.y;
  const int t = threadIdx.x;
  const int lane = t & 63, wv = t >> 6;
  const int l15 = lane & 15, q = lane >> 4;
  const int qs = (q ^ ((l15 >> 1) & 3)) * 8;
  const int wm = (wv & 3) * 64;
  const int wn = (wv >> 2) * 64;
  const unsigned short* xTb = xT + ((size_t)b * NSP + n0) * CIN;
  const unsigned short* abase = wcomb + (size_t)b * 256 * 256;
  const int sn = t >> 2, sc8 = t & 3;
  const int sc8s = sc8 ^ ((sn >> 1) & 3);
  const unsigned short* sg = xTb + (size_t)sn * CIN + sc8s * 8;
  unsigned short* sl = &Sx[0][0] + t * 8;
  f32x4 acc[4][4];
#pragma unroll
  for (int i = 0; i < 4; ++i)
#pragma unroll
    for (int j = 0; j < 4; ++j) acc[i][j] = 0.0f;

  gload_lds16(sg + 0 * 32, sl + 0 * 4096);
  gload_lds16(sg + 1 * 32, sl + 1 * 4096);
  asm volatile("s_waitcnt vmcnt(1)" ::: "memory");
  __builtin_amdgcn_s_barrier();
  FENCE();

#pragma unroll
  for (int kc = 0; kc < 6; ++kc) {
    bfrag a[4];
#pragma unroll
    for (int mi = 0; mi < 4; ++mi)
      a[mi] = *(const bfrag*)(abase + (size_t)(wm + mi * 16 + l15) * 256 + kc * 32 + q * 8);
    gload_lds16(sg + (kc + 2) * 32, sl + ((kc + 2) & 3) * 4096);
    const unsigned short* bufp = &Sx[kc & 3][0];
#pragma unroll
    for (int ni = 0; ni < 4; ++ni) {
      bfrag bbv = *(const bfrag*)(bufp + (wn + ni * 16 + l15) * 32 + qs);
#pragma unroll
      for (int mi = 0; mi < 4; ++mi)
        acc[mi][ni] = __builtin_amdgcn_mfma_f32_16x16x32_bf16(a[mi], bbv, acc[mi][ni], 0, 0, 0);
    }
    asm volatile("s_waitcnt vmcnt(1)" ::: "memory");
    __builtin_amdgcn_s_barrier();
    FENCE();
  }
  {  // kc = 6
    bfrag a[4];
#pragma unroll
    for (int mi = 0; mi < 4; ++mi)
      a[mi] = *(const bfrag*)(abase + (size_t)(wm + mi * 16 + l15) * 256 + 6 * 32 + q * 8);
    const unsigned short* bufp = &Sx[2][0];
#pragma unroll
    for (int ni = 0; ni < 4; ++ni) {
      bfrag bbv = *(const bfrag*)(bufp + (wn + ni * 16 + l15) * 32 + qs);
#pragma unroll
      for (int mi = 0; mi < 4; ++mi)
        acc[mi][ni] = __builtin_amdgcn_mfma_f32_16x16x32_bf16(a[mi], bbv, acc[mi][ni], 0, 0, 0);
    }
    asm volatile("s_waitcnt vmcnt(0)" ::: "memory");
    __builtin_amdgcn_s_barrier();
    FENCE();
  }
  {  // kc = 7
    bfrag a[4];
#pragma unroll
    for (int mi = 0; mi < 4; ++mi)
      a[mi] = *(const bfrag*)(abase + (size_t)(wm + mi * 16 + l15) * 256 + 7 * 32 + q * 8);
    const unsigned short* bufp = &Sx[3][0];
#pragma unroll
    for (int ni = 0; ni < 4; ++ni) {
      bfrag bbv = *(const bfrag*)(bufp + (wn + ni * 16 + l15) * 32 + qs);
#pragma unroll
      for (int mi = 0; mi < 4; ++mi)
        acc[mi][ni] = __builtin_amdgcn_mfma_f32_16x16x32_bf16(a[mi], bbv, acc[mi][ni], 0, 0, 0);
    }
  }
  float* obase = out + (size_t)b * 256 * NSP;
#pragma unroll
  for (int mi = 0; mi < 4; ++mi) {
    const int ob = wm + mi * 16 + q * 4;
    const float4 bias = *(const float4*)(b_out + ob);
    float ba[4] = {bias.x, bias.y, bias.z, bias.w};
#pragma unroll
    for (int ni = 0; ni < 4; ++ni) {
      const int n = n0 + wn + ni * 16 + l15;
#pragma unroll
      for (int rg = 0; rg < 4; ++rg)
        obase[(size_t)(ob + rg) * NSP + n] = acc[mi][ni][rg] + ba[rg];
    }
  }
}

// ---------------- workspace layout ----------------
// xT    : 0        , 67108864 B  (B*N*C bf16, written by la_pass1)
// wkvb  : 67108864 , 131072 B    (256x256 bf16 k/v weights)
// ctxu  : 67239936 , 131072 B    (fp32, zeroed by la_prep)
// sums  : 67371008 , 4096 B      (fp32, zeroed by la_prep; contiguous with ctxu)
// wcomb : 67375104 , 1048576 B   (bf16)
// total ~65.3 MB

extern "C" void kernel_launch(void* const* d_in, const int* in_sizes, int n_in,
                              void* d_out, int out_size, void* d_ws, size_t ws_size,
                              hipStream_t stream) {
  (void)in_sizes; (void)n_in; (void)out_size; (void)ws_size;
  const float* x     = (const float*)d_in[0];
  const float* w_qkv = (const float*)d_in[1];
  const float* w_out = (const float*)d_in[2];
  const float* b_out = (const float*)d_in[3];
  float* out = (float*)d_out;
  char* ws = (char*)d_ws;
  unsigned short* xTws  = (unsigned short*)(ws);
  unsigned short* wkvb  = (unsigned short*)(ws + 67108864);
  float* ctxu           = (float*)(ws + 67239936);
  float* sums           = (float*)(ws + 67371008);
  unsigned short* wcomb = (unsigned short*)(ws + 67375104);

  la_prep<<<dim3(65), dim3(256), 0, stream>>>(w_qkv, wkvb, ctxu);
  la_pass1<<<dim3(NSP / 128, BB), dim3(512), 0, stream>>>(x, wkvb, xTws, ctxu, sums);
  la_mid<<<dim3(256, BB), dim3(256), 0, stream>>>(w_out, ctxu, sums, w_qkv, wcomb);
  la_out<<<dim3(NSP / 128, BB), dim3(512), 0, stream>>>(wcomb, xTws, b_out, out);
}

// Round 9
// 390.721 us; speedup vs baseline: 1.0235x; 1.0235x over previous
//
#include <hip/hip_runtime.h>
#include <stdint.h>

#define BB 8
#define CIN 256
#define NSP 16384      // H*W
#define HID 128

typedef __bf16 bfrag __attribute__((ext_vector_type(8)));
typedef float  f32x4 __attribute__((ext_vector_type(4)));

__device__ __forceinline__ unsigned short f2bf(float f) {
  union { float f; unsigned int u; } v; v.f = f;
  unsigned int u = v.u;
  return (unsigned short)((u + 0x7FFFu + ((u >> 16) & 1u)) >> 16);  // RNE
}

// ---------------- prep: wkvb = bf16(w_qkv rows 128..383); zero ctxu+sums ----------------
__global__ __launch_bounds__(256) void la_prep(const float* __restrict__ w_qkv,
                                               unsigned short* __restrict__ wkvb,
                                               float* __restrict__ zbase) {
  const int blk = blockIdx.x;
  const int t = threadIdx.x;
  if (blk < 64) {
    const int off = (blk * 256 + t) * 4;   // 0..65532
    const float4 wv4 = *(const float4*)(w_qkv + (size_t)128 * CIN + off);
    ushort4 p;
    p.x = f2bf(wv4.x); p.y = f2bf(wv4.y); p.z = f2bf(wv4.z); p.w = f2bf(wv4.w);
    *(ushort4*)(wkvb + off) = p;
  } else {
    // zero ctxu (32768 f) + sums (1024 f) contiguous = 8448 float4
    for (int i = t; i < 8448; i += 256) {
      float4 z = {0.f, 0.f, 0.f, 0.f};
      *(float4*)(zbase + i * 4) = z;
    }
  }
}

// ---------------- pass 1: k/v GEMM + exp + row-sums + register-local ctx -> atomics ----------------
// Block: 64-n tile of one batch, 512 threads = 8 waves, 3+ blocks/CU (acc = 32 AGPR).
// GEMM: M=256 (k rows 0..127, v rows 128..255 of wkvb), K=256, N=64.
// Wave wv owns k-band [wv*16,+16) and v-band [128+wv*16,+16): acc[2][4].
// Epilogue: exp -> sums atomics; Lk/Lv (128x64) staged in ONE phase; each wave owns
// 2 ctx tiles (h=wv>>1, dt=wv&1, et=0..1) exclusively -> AGPR results straight to ctxu atomics.
__global__ __launch_bounds__(512, 6) void la_fused(const float* __restrict__ x,
                                                   const unsigned short* __restrict__ wkvb,
                                                   float* __restrict__ ctxu,
                                                   float* __restrict__ sums) {
  __shared__ __align__(16) union {
    unsigned short Xb[2][64][40];                                  // 10240 B staging (dbuf)
    struct { unsigned short Lk[128][72]; unsigned short Lv[128][72]; } e;  // 36864 B
  } sh;
  const int chunk = blockIdx.x;
  const int n0 = chunk * 64;
  const int b = blockIdx.y;
  const int t = threadIdx.x;
  const int lane = t & 63, wv = t >> 6;
  const int l15 = lane & 15, q = lane >> 4;
  const int scl = t >> 4;          // c within 32-chunk
  const int snf = (t & 15) * 4;    // 4 n per thread
  const float* xp = x + (size_t)b * CIN * NSP + n0;
  f32x4 acc[2][4];
#pragma unroll
  for (int i = 0; i < 2; ++i)
#pragma unroll
    for (int j = 0; j < 4; ++j) acc[i][j] = 0.0f;

#define STOREX(B, A) do {                         \
    sh.Xb[B][snf + 0][scl] = f2bf((A).x);         \
    sh.Xb[B][snf + 1][scl] = f2bf((A).y);         \
    sh.Xb[B][snf + 2][scl] = f2bf((A).z);         \
    sh.Xb[B][snf + 3][scl] = f2bf((A).w);         \
  } while (0)

  float4 xa;
  xa = *(const float4*)(xp + (size_t)scl * NSP + snf);          // kc=0
  STOREX(0, xa);
  xa = *(const float4*)(xp + (size_t)(32 + scl) * NSP + snf);   // kc=1
  __syncthreads();

#pragma unroll
  for (int kc = 0; kc < 8; ++kc) {
    const int buf = kc & 1;
    if (kc < 7) {
      STOREX(buf ^ 1, xa);
      if (kc < 6) xa = *(const float4*)(xp + (size_t)((kc + 2) * 32 + scl) * NSP + snf);
    }
    const bfrag a0 = *(const bfrag*)(wkvb + (size_t)(wv * 16 + l15) * CIN + kc * 32 + q * 8);
    const bfrag a1 = *(const bfrag*)(wkvb + (size_t)(128 + wv * 16 + l15) * CIN + kc * 32 + q * 8);
#pragma unroll
    for (int nf = 0; nf < 4; ++nf) {
      const bfrag bb = *(const bfrag*)&sh.Xb[buf][nf * 16 + l15][q * 8];
      acc[0][nf] = __builtin_amdgcn_mfma_f32_16x16x32_bf16(a0, bb, acc[0][nf], 0, 0, 0);
      acc[1][nf] = __builtin_amdgcn_mfma_f32_16x16x32_bf16(a1, bb, acc[1][nf], 0, 0, 0);
    }
    __syncthreads();
  }
#undef STOREX

  // ---- exp in place on k accumulators ----
#pragma unroll
  for (int nf = 0; nf < 4; ++nf)
#pragma unroll
    for (int rg = 0; rg < 4; ++rg) acc[0][nf][rg] = __expf(acc[0][nf][rg]);

  // ---- k row-sums of exp -> atomic ----
#pragma unroll
  for (int rg = 0; rg < 4; ++rg) {
    float s = acc[0][0][rg] + acc[0][1][rg] + acc[0][2][rg] + acc[0][3][rg];
    s += __shfl_down(s, 8, 16);
    s += __shfl_down(s, 4, 16);
    s += __shfl_down(s, 2, 16);
    s += __shfl_down(s, 1, 16);
    if (l15 == 0) atomicAdd(&sums[b * 128 + wv * 16 + q * 4 + rg], s);
  }

  // ---- stage Lk/Lv (single phase; union with Xb is safe: last barrier passed) ----
#pragma unroll
  for (int nf = 0; nf < 4; ++nf)
#pragma unroll
    for (int rg = 0; rg < 4; ++rg) {
      sh.e.Lk[wv * 16 + q * 4 + rg][nf * 16 + l15] = f2bf(acc[0][nf][rg]);
      sh.e.Lv[wv * 16 + q * 4 + rg][nf * 16 + l15] = f2bf(acc[1][nf][rg]);
    }
  __syncthreads();

  // ---- ctx: wave owns tiles (h=wv>>1, dt=wv&1, et=0/1); K=64 -> 2 k-steps ----
  {
    const int h = wv >> 1, dt = wv & 1;
    const bfrag ak0 = *(const bfrag*)&sh.e.Lk[h * 32 + dt * 16 + l15][q * 8];
    const bfrag ak1 = *(const bfrag*)&sh.e.Lk[h * 32 + dt * 16 + l15][32 + q * 8];
    float* cub = ctxu + (size_t)b * 4096 + h * 1024;
#pragma unroll
    for (int et = 0; et < 2; ++et) {
      const bfrag bv0 = *(const bfrag*)&sh.e.Lv[h * 32 + et * 16 + l15][q * 8];
      const bfrag bv1 = *(const bfrag*)&sh.e.Lv[h * 32 + et * 16 + l15][32 + q * 8];
      f32x4 ct = {0.f, 0.f, 0.f, 0.f};
      ct = __builtin_amdgcn_mfma_f32_16x16x32_bf16(ak0, bv0, ct, 0, 0, 0);
      ct = __builtin_amdgcn_mfma_f32_16x16x32_bf16(ak1, bv1, ct, 0, 0, 0);
#pragma unroll
      for (int rg = 0; rg < 4; ++rg)
        atomicAdd(&cub[(dt * 16 + q * 4 + rg) * 32 + et * 16 + l15], ct[rg]);
    }
  }
}

// ---------------- mid: weff row (in LDS) -> wcomb row, fused ----------------
__global__ __launch_bounds__(256) void la_mid(const float* __restrict__ w_out,
                                              const float* __restrict__ ctxu,
                                              const float* __restrict__ sums,
                                              const float* __restrict__ w_qkv,
                                              unsigned short* __restrict__ wcomb) {
  __shared__ float wrow[128];
  const int o = blockIdx.x;
  const int b = blockIdx.y;
  const int t = threadIdx.x;
  if (t < 128) {
    const int h = t >> 5, d = t & 31;
    const float* wr = w_out + (size_t)o * HID + h * 32;
    const float* cr = ctxu + ((size_t)(b * 4 + h) * 32 + d) * 32;
    float s = 0.f;
#pragma unroll 8
    for (int e = 0; e < 32; ++e) s += wr[e] * cr[e];
    wrow[t] = s * (1.0f / sums[b * 128 + t]);
  }
  __syncthreads();
  float s = 0.f;
#pragma unroll 8
  for (int hd = 0; hd < 128; ++hd) s += wrow[hd] * w_qkv[(size_t)hd * CIN + t];
  wcomb[((size_t)b * 256 + o) * 256 + t] = f2bf(s);
}

// ---------------- out[b][o][n] = sum_c Wcomb[b][o][c] * x[b][c][n] + b_out[o] ----------------
// Block: 64-n tile, M=256, 512 threads = 8 waves (wave = 64m x 32n, acc[4][2] = 32 AGPR).
__global__ __launch_bounds__(512, 6) void la_out(const unsigned short* __restrict__ wcomb,
                                                 const float* __restrict__ x,
                                                 const float* __restrict__ b_out,
                                                 float* __restrict__ out) {
  __shared__ __align__(16) unsigned short Bt[2][64][40];   // 10240 B
  const int n0 = blockIdx.x * 64;
  const int b = blockIdx.y;
  const int t = threadIdx.x;
  const int lane = t & 63, wv = t >> 6;
  const int l15 = lane & 15, q = lane >> 4;
  const int wm = (wv & 3) * 64;
  const int wn = (wv >> 2) * 32;
  const int scl = t >> 4, snf = (t & 15) * 4;
  const float* xp = x + (size_t)b * CIN * NSP + n0;
  const unsigned short* abase = wcomb + (size_t)b * 256 * 256;
  f32x4 acc[4][2];
#pragma unroll
  for (int i = 0; i < 4; ++i)
#pragma unroll
    for (int j = 0; j < 2; ++j) acc[i][j] = 0.0f;

#define STOREB(B, A) do {                     \
    Bt[B][snf + 0][scl] = f2bf((A).x);        \
    Bt[B][snf + 1][scl] = f2bf((A).y);        \
    Bt[B][snf + 2][scl] = f2bf((A).z);        \
    Bt[B][snf + 3][scl] = f2bf((A).w);        \
  } while (0)

  float4 xa;
  xa = *(const float4*)(xp + (size_t)scl * NSP + snf);
  STOREB(0, xa);
  xa = *(const float4*)(xp + (size_t)(32 + scl) * NSP + snf);
  __syncthreads();

#pragma unroll
  for (int kc = 0; kc < 8; ++kc) {
    const int buf = kc & 1;
    if (kc < 7) {
      STOREB(buf ^ 1, xa);
      if (kc < 6) xa = *(const float4*)(xp + (size_t)((kc + 2) * 32 + scl) * NSP + snf);
    }
    bfrag a[4];
#pragma unroll
    for (int mi = 0; mi < 4; ++mi)
      a[mi] = *(const bfrag*)(abase + (size_t)(wm + mi * 16 + l15) * 256 + kc * 32 + q * 8);
#pragma unroll
    for (int ni = 0; ni < 2; ++ni) {
      const bfrag bb = *(const bfrag*)&Bt[buf][wn + ni * 16 + l15][q * 8];
#pragma unroll
      for (int mi = 0; mi < 4; ++mi)
        acc[mi][ni] = __builtin_amdgcn_mfma_f32_16x16x32_bf16(a[mi], bb, acc[mi][ni], 0, 0, 0);
    }
    __syncthreads();
  }
#undef STOREB

  float* obase = out + (size_t)b * 256 * NSP;
#pragma unroll
  for (int mi = 0; mi < 4; ++mi) {
    const int ob = wm + mi * 16 + q * 4;
    const float4 bias = *(const float4*)(b_out + ob);
    float ba[4] = {bias.x, bias.y, bias.z, bias.w};
#pragma unroll
    for (int ni = 0; ni < 2; ++ni) {
      const int n = n0 + wn + ni * 16 + l15;
#pragma unroll
      for (int rg = 0; rg < 4; ++rg)
        obase[(size_t)(ob + rg) * NSP + n] = acc[mi][ni][rg] + ba[rg];
    }
  }
}

// ---------------- workspace layout ----------------
// wkvb  : 0        , 131072 B   (256x256 bf16 k/v weights)
// ctxu  : 131072   , 131072 B   (fp32, zeroed by la_prep)
// sums  : 262144   , 4096 B     (fp32, zeroed by la_prep; contiguous with ctxu)
// wcomb : 266240   , 1048576 B  (bf16)
// total ~1.3 MB

extern "C" void kernel_launch(void* const* d_in, const int* in_sizes, int n_in,
                              void* d_out, int out_size, void* d_ws, size_t ws_size,
                              hipStream_t stream) {
  (void)in_sizes; (void)n_in; (void)out_size; (void)ws_size;
  const float* x     = (const float*)d_in[0];
  const float* w_qkv = (const float*)d_in[1];
  const float* w_out = (const float*)d_in[2];
  const float* b_out = (const float*)d_in[3];
  float* out = (float*)d_out;
  char* ws = (char*)d_ws;
  unsigned short* wkvb  = (unsigned short*)(ws);
  float* ctxu           = (float*)(ws + 131072);
  float* sums           = (float*)(ws + 262144);
  unsigned short* wcomb = (unsigned short*)(ws + 266240);

  la_prep<<<dim3(65), dim3(256), 0, stream>>>(w_qkv, wkvb, ctxu);
  la_fused<<<dim3(NSP / 64, BB), dim3(512), 0, stream>>>(x, wkvb, ctxu, sums);
  la_mid<<<dim3(256, BB), dim3(256), 0, stream>>>(w_out, ctxu, sums, w_qkv, wcomb);
  la_out<<<dim3(NSP / 64, BB), dim3(512), 0, stream>>>(wcomb, x, b_out, out);
}

// Round 12
// 319.359 us; speedup vs baseline: 1.2523x; 1.2235x over previous
//
#include <hip/hip_runtime.h>
#include <stdint.h>

#define BB 8
#define CIN 256
#define NSP 16384      // H*W
#define HID 128

typedef __bf16 bfrag __attribute__((ext_vector_type(8)));
typedef float  f32x4 __attribute__((ext_vector_type(4)));

__device__ __forceinline__ unsigned short f2bf(float f) {
  union { float f; unsigned int u; } v; v.f = f;
  unsigned int u = v.u;
  return (unsigned short)((u + 0x7FFFu + ((u >> 16) & 1u)) >> 16);  // RNE
}

// ---------------- prep: wkvb = bf16(w_qkv rows 128..383) ----------------
// (no zeroing needed anymore: all partial buffers are fully overwritten non-atomically)
__global__ __launch_bounds__(256) void la_prep(const float* __restrict__ w_qkv,
                                               unsigned short* __restrict__ wkvb) {
  const int blk = blockIdx.x;
  const int t = threadIdx.x;
  const int off = (blk * 256 + t) * 4;   // 0..65532
  const float4 wv4 = *(const float4*)(w_qkv + (size_t)128 * CIN + off);
  ushort4 p;
  p.x = f2bf(wv4.x); p.y = f2bf(wv4.y); p.z = f2bf(wv4.z); p.w = f2bf(wv4.w);
  *(ushort4*)(wkvb + off) = p;
}

// ---------------- pass 1: k/v GEMM + exp + row-sum partials + context partials ----------------
// ROUND-2 STRUCTURE (proven best: 86 us): 128-n tile, 512 threads = 8 waves,
// M=256 (k rows 0..127, v rows 128..255 of wkvb), K=256, N=128.
// A-fragments direct from global bf16 wkvb (L2-resident); Xb double-buffered, 1 barrier/kc.
// CHANGED vs round 2: NO GLOBAL ATOMICS. Row-sums -> sumsp[b][chunk][128] (exclusive),
// ctx quarter-combined in LDS -> ctxp[b][chunk][4096] (exclusive, coalesced).
// Lk/Lv pad 136->140: makes the epilogue b16 writes conflict-free (disjoint 8-bank windows).
__global__ __launch_bounds__(512, 4) void la_fused(const float* __restrict__ x,
                                                   const unsigned short* __restrict__ wkvb,
                                                   float* __restrict__ ctxp,
                                                   float* __restrict__ sumsp) {
  __shared__ __align__(16) union {
    struct { unsigned short Xb[2][128][40]; } g;                              // 20480 B
    struct { unsigned short Lk[64][140]; unsigned short Lv[64][140];
             float Pc[4][1024]; } e;                                          // 52224 B
  } sh;
  const int chunk = blockIdx.x;
  const int n0 = chunk * 128;
  const int b = blockIdx.y;
  const int t = threadIdx.x;
  const int lane = t & 63, wv = t >> 6;
  const int l15 = lane & 15, q = lane >> 4;
  const int cl = t & 31;
  const int n16 = (t >> 5) * 8;
  const float* xp = x + (size_t)b * CIN * NSP + n0;
  f32x4 acc[2][8];
#pragma unroll
  for (int i = 0; i < 2; ++i)
#pragma unroll
    for (int j = 0; j < 8; ++j) acc[i][j] = 0.0f;

  // prologue: load cols(kc=0), stage Xb[0], load cols(kc=1)
  float4 xa0, xa1;
  {
    const float* xr = xp + (size_t)cl * NSP + n16;
    xa0 = *(const float4*)xr;
    xa1 = *(const float4*)(xr + 4);
  }
  {
    sh.g.Xb[0][n16 + 0][cl] = f2bf(xa0.x);
    sh.g.Xb[0][n16 + 1][cl] = f2bf(xa0.y);
    sh.g.Xb[0][n16 + 2][cl] = f2bf(xa0.z);
    sh.g.Xb[0][n16 + 3][cl] = f2bf(xa0.w);
    sh.g.Xb[0][n16 + 4][cl] = f2bf(xa1.x);
    sh.g.Xb[0][n16 + 5][cl] = f2bf(xa1.y);
    sh.g.Xb[0][n16 + 6][cl] = f2bf(xa1.z);
    sh.g.Xb[0][n16 + 7][cl] = f2bf(xa1.w);
    const float* xr = xp + (size_t)(32 + cl) * NSP + n16;
    xa0 = *(const float4*)xr;
    xa1 = *(const float4*)(xr + 4);
  }
  __syncthreads();

#pragma unroll
  for (int kc = 0; kc < 8; ++kc) {
    const int p = kc & 1;
    // A-fragments: direct global loads from bf16 wkvb (L2-resident)
    bfrag a0 = *(const bfrag*)(wkvb + (size_t)(wv * 16 + l15) * CIN + kc * 32 + q * 8);
    bfrag a1 = *(const bfrag*)(wkvb + (size_t)(128 + wv * 16 + l15) * CIN + kc * 32 + q * 8);
    // stage next kc tile into the other buffer (regs loaded last iteration)
    if (kc < 7) {
      sh.g.Xb[p ^ 1][n16 + 0][cl] = f2bf(xa0.x);
      sh.g.Xb[p ^ 1][n16 + 1][cl] = f2bf(xa0.y);
      sh.g.Xb[p ^ 1][n16 + 2][cl] = f2bf(xa0.z);
      sh.g.Xb[p ^ 1][n16 + 3][cl] = f2bf(xa0.w);
      sh.g.Xb[p ^ 1][n16 + 4][cl] = f2bf(xa1.x);
      sh.g.Xb[p ^ 1][n16 + 5][cl] = f2bf(xa1.y);
      sh.g.Xb[p ^ 1][n16 + 6][cl] = f2bf(xa1.z);
      sh.g.Xb[p ^ 1][n16 + 7][cl] = f2bf(xa1.w);
      if (kc < 6) {
        const float* xr = xp + (size_t)((kc + 2) * 32 + cl) * NSP + n16;
        xa0 = *(const float4*)xr;
        xa1 = *(const float4*)(xr + 4);
      }
    }
#pragma unroll
    for (int ni = 0; ni < 8; ++ni) {
      bfrag bbv = *(const bfrag*)&sh.g.Xb[p][ni * 16 + l15][q * 8];
      acc[0][ni] = __builtin_amdgcn_mfma_f32_16x16x32_bf16(a0, bbv, acc[0][ni], 0, 0, 0);
      acc[1][ni] = __builtin_amdgcn_mfma_f32_16x16x32_bf16(a1, bbv, acc[1][ni], 0, 0, 0);
    }
    __syncthreads();
  }

  // ---- exp in place on k accumulators ----
#pragma unroll
  for (int ni = 0; ni < 8; ++ni)
#pragma unroll
    for (int rg = 0; rg < 4; ++rg) acc[0][ni][rg] = __expf(acc[0][ni][rg]);

  // ---- k row-sum PARTIALS (this chunk's 128 n) -> exclusive sumsp slot, NO atomics ----
  {
    float sp[4] = {0.f, 0.f, 0.f, 0.f};
#pragma unroll
    for (int ni = 0; ni < 8; ++ni)
#pragma unroll
      for (int rg = 0; rg < 4; ++rg) sp[rg] += acc[0][ni][rg];
#pragma unroll
    for (int rg = 0; rg < 4; ++rg) {
      float s = sp[rg];
      s += __shfl_down(s, 8, 16);
      s += __shfl_down(s, 4, 16);
      s += __shfl_down(s, 2, 16);
      s += __shfl_down(s, 1, 16);
      if (l15 == 0)
        sumsp[((size_t)b * 128 + chunk) * 128 + wv * 16 + q * 4 + rg] = s;
    }
  }
  // ---- context, two 64-row phases (LDS budget); combine quarters in LDS,
  //      store exclusive ctxp slice (coalesced), NO atomics ----
  float* cp = ctxp + ((size_t)b * 128 + chunk) * 4096;
#pragma unroll
  for (int ph = 0; ph < 2; ++ph) {
    if ((wv >> 2) == ph) {
      const int r = (wv & 3) * 16 + q * 4;
#pragma unroll
      for (int ni = 0; ni < 8; ++ni)
#pragma unroll
        for (int rg = 0; rg < 4; ++rg) {
          sh.e.Lk[r + rg][ni * 16 + l15] = f2bf(acc[0][ni][rg]);   // already exp'd
          sh.e.Lv[r + rg][ni * 16 + l15] = f2bf(acc[1][ni][rg]);
        }
    }
    __syncthreads();
    const int hl = wv >> 2, nq = wv & 3;
    f32x4 c2[2][2];
    c2[0][0] = 0.f; c2[0][1] = 0.f; c2[1][0] = 0.f; c2[1][1] = 0.f;
    bfrag ka[2], vb[2];
#pragma unroll
    for (int d2 = 0; d2 < 2; ++d2)
      ka[d2] = *(const bfrag*)&sh.e.Lk[hl * 32 + d2 * 16 + l15][nq * 32 + q * 8];
#pragma unroll
    for (int e2 = 0; e2 < 2; ++e2)
      vb[e2] = *(const bfrag*)&sh.e.Lv[hl * 32 + e2 * 16 + l15][nq * 32 + q * 8];
#pragma unroll
    for (int d2 = 0; d2 < 2; ++d2)
#pragma unroll
      for (int e2 = 0; e2 < 2; ++e2)
        c2[d2][e2] = __builtin_amdgcn_mfma_f32_16x16x32_bf16(ka[d2], vb[e2], c2[d2][e2], 0, 0, 0);
    const int slot = hl * 2 + (nq & 1);
    if (nq < 2) {
#pragma unroll
      for (int d2 = 0; d2 < 2; ++d2)
#pragma unroll
        for (int e2 = 0; e2 < 2; ++e2)
#pragma unroll
          for (int rg = 0; rg < 4; ++rg)
            sh.e.Pc[slot][(d2 * 16 + q * 4 + rg) * 32 + e2 * 16 + l15] = c2[d2][e2][rg];
    }
    __syncthreads();
    if (nq >= 2) {
#pragma unroll
      for (int d2 = 0; d2 < 2; ++d2)
#pragma unroll
        for (int e2 = 0; e2 < 2; ++e2)
#pragma unroll
          for (int rg = 0; rg < 4; ++rg)
            sh.e.Pc[slot][(d2 * 16 + q * 4 + rg) * 32 + e2 * 16 + l15] += c2[d2][e2][rg];
    }
    __syncthreads();
    for (int idx = t; idx < 2048; idx += 512) {
      const int h2 = idx >> 10, pos = idx & 1023;
      cp[(ph * 2 + h2) * 1024 + pos] = sh.e.Pc[h2 * 2][pos] + sh.e.Pc[h2 * 2 + 1][pos];
    }
    __syncthreads();
  }
}

// ---------------- reduce: ctxp over 128 chunks -> ctxu; sumsp over 128 chunks -> sums ----------------
__global__ __launch_bounds__(256) void la_reduce(const float* __restrict__ ctxp,
                                                 const float* __restrict__ sumsp,
                                                 float* __restrict__ ctxu,
                                                 float* __restrict__ sums) {
  const int blk = blockIdx.x;
  const int t = threadIdx.x;
  if (blk < 128) {
    const int gid = blk * 256 + t;            // 0..32767
    const int b = gid >> 12, pos = gid & 4095;
    const float* base = ctxp + (size_t)b * 128 * 4096 + pos;
    float s = 0.f;
#pragma unroll 8
    for (int c = 0; c < 128; ++c) s += base[(size_t)c * 4096];
    ctxu[gid] = s;
  } else {
    const int gid = (blk - 128) * 256 + t;    // 0..1023
    const int b = gid >> 7, row = gid & 127;
    const float* base = sumsp + (size_t)b * 128 * 128 + row;
    float s = 0.f;
#pragma unroll 8
    for (int c = 0; c < 128; ++c) s += base[c * 128];
    sums[gid] = s;
  }
}

// ---------------- mid: weff row (in LDS) -> wcomb row, fused (unchanged from round 2) ----------------
__global__ __launch_bounds__(256) void la_mid(const float* __restrict__ w_out,
                                              const float* __restrict__ ctxu,
                                              const float* __restrict__ sums,
                                              const float* __restrict__ w_qkv,
                                              unsigned short* __restrict__ wcomb) {
  __shared__ float wrow[128];
  const int o = blockIdx.x;
  const int b = blockIdx.y;
  const int t = threadIdx.x;
  if (t < 128) {
    const int h = t >> 5, d = t & 31;
    const float* wr = w_out + (size_t)o * HID + h * 32;
    const float* cr = ctxu + ((size_t)(b * 4 + h) * 32 + d) * 32;
    float s = 0.f;
#pragma unroll 8
    for (int e = 0; e < 32; ++e) s += wr[e] * cr[e];
    wrow[t] = s * (1.0f / sums[b * 128 + t]);
  }
  __syncthreads();
  float s = 0.f;
#pragma unroll 8
  for (int hd = 0; hd < 128; ++hd) s += wrow[hd] * w_qkv[(size_t)hd * CIN + t];
  wcomb[((size_t)b * 256 + o) * 256 + t] = f2bf(s);
}

// ---------------- out[b][o][n] = sum_c Wcomb[b][o][c] * x[b][c][n] + b_out[o] ----------------
// UNCHANGED from round 2: M=256 per block, N=128, 8 waves (64m x 64n), Bt dbuf, 1 barrier/kc.
__global__ __launch_bounds__(512, 4) void la_out(const unsigned short* __restrict__ wcomb,
                                                 const float* __restrict__ x,
                                                 const float* __restrict__ b_out,
                                                 float* __restrict__ out) {
  __shared__ __align__(16) unsigned short Bt[2][128][40];   // 20480 B
  const int n0 = blockIdx.x * 128;
  const int b = blockIdx.y;
  const int t = threadIdx.x;
  const int lane = t & 63, wv = t >> 6;
  const int l15 = lane & 15, q = lane >> 4;
  const int wm = (wv & 3) * 64;
  const int wn = (wv >> 2) * 64;
  const int cl = t & 31, n16 = (t >> 5) * 8;
  const float* xp = x + (size_t)b * CIN * NSP + n0;
  const unsigned short* abase = wcomb + (size_t)b * 256 * 256;
  f32x4 acc[4][4];
#pragma unroll
  for (int i = 0; i < 4; ++i)
#pragma unroll
    for (int j = 0; j < 4; ++j) acc[i][j] = 0.0f;

  float4 xa0, xa1;
  {
    const float* xr = xp + (size_t)cl * NSP + n16;
    xa0 = *(const float4*)xr;
    xa1 = *(const float4*)(xr + 4);
  }
  {
    Bt[0][n16 + 0][cl] = f2bf(xa0.x);
    Bt[0][n16 + 1][cl] = f2bf(xa0.y);
    Bt[0][n16 + 2][cl] = f2bf(xa0.z);
    Bt[0][n16 + 3][cl] = f2bf(xa0.w);
    Bt[0][n16 + 4][cl] = f2bf(xa1.x);
    Bt[0][n16 + 5][cl] = f2bf(xa1.y);
    Bt[0][n16 + 6][cl] = f2bf(xa1.z);
    Bt[0][n16 + 7][cl] = f2bf(xa1.w);
    const float* xr = xp + (size_t)(32 + cl) * NSP + n16;
    xa0 = *(const float4*)xr;
    xa1 = *(const float4*)(xr + 4);
  }
  __syncthreads();

#pragma unroll
  for (int kc = 0; kc < 8; ++kc) {
    const int p = kc & 1;
    bfrag a[4];
#pragma unroll
    for (int mi = 0; mi < 4; ++mi)
      a[mi] = *(const bfrag*)(abase + (size_t)(wm + mi * 16 + l15) * 256 + kc * 32 + q * 8);
    if (kc < 7) {
      Bt[p ^ 1][n16 + 0][cl] = f2bf(xa0.x);
      Bt[p ^ 1][n16 + 1][cl] = f2bf(xa0.y);
      Bt[p ^ 1][n16 + 2][cl] = f2bf(xa0.z);
      Bt[p ^ 1][n16 + 3][cl] = f2bf(xa0.w);
      Bt[p ^ 1][n16 + 4][cl] = f2bf(xa1.x);
      Bt[p ^ 1][n16 + 5][cl] = f2bf(xa1.y);
      Bt[p ^ 1][n16 + 6][cl] = f2bf(xa1.z);
      Bt[p ^ 1][n16 + 7][cl] = f2bf(xa1.w);
      if (kc < 6) {
        const float* xr = xp + (size_t)((kc + 2) * 32 + cl) * NSP + n16;
        xa0 = *(const float4*)xr;
        xa1 = *(const float4*)(xr + 4);
      }
    }
#pragma unroll
    for (int ni = 0; ni < 4; ++ni) {
      bfrag bbv = *(const bfrag*)&Bt[p][wn + ni * 16 + l15][q * 8];
#pragma unroll
      for (int mi = 0; mi < 4; ++mi)
        acc[mi][ni] = __builtin_amdgcn_mfma_f32_16x16x32_bf16(a[mi], bbv, acc[mi][ni], 0, 0, 0);
    }
    __syncthreads();
  }
  float* obase = out + (size_t)b * 256 * NSP;
#pragma unroll
  for (int mi = 0; mi < 4; ++mi) {
    const int ob = wm + mi * 16 + q * 4;
    const float4 bias = *(const float4*)(b_out + ob);
    float ba[4] = {bias.x, bias.y, bias.z, bias.w};
#pragma unroll
    for (int ni = 0; ni < 4; ++ni) {
      const int n = n0 + wn + ni * 16 + l15;
#pragma unroll
      for (int rg = 0; rg < 4; ++rg)
        obase[(size_t)(ob + rg) * NSP + n] = acc[mi][ni][rg] + ba[rg];
    }
  }
}

// ---------------- workspace layout ----------------
// wkvb  : 0        , 131072 B    (256x256 bf16 k/v weights)
// ctxp  : 131072   , 16777216 B  (fp32 [b][chunk][4096], fully overwritten)
// sumsp : 16908288 , 524288 B    (fp32 [b][chunk][128], fully overwritten)
// ctxu  : 17432576 , 131072 B
// sums  : 17563648 , 4096 B
// wcomb : 17567744 , 1048576 B   (bf16)
// total ~18.6 MB

extern "C" void kernel_launch(void* const* d_in, const int* in_sizes, int n_in,
                              void* d_out, int out_size, void* d_ws, size_t ws_size,
                              hipStream_t stream) {
  (void)in_sizes; (void)n_in; (void)out_size; (void)ws_size;
  const float* x     = (const float*)d_in[0];
  const float* w_qkv = (const float*)d_in[1];
  const float* w_out = (const float*)d_in[2];
  const float* b_out = (const float*)d_in[3];
  float* out = (float*)d_out;
  char* ws = (char*)d_ws;
  unsigned short* wkvb  = (unsigned short*)(ws);
  float* ctxp           = (float*)(ws + 131072);
  float* sumsp          = (float*)(ws + 16908288);
  float* ctxu           = (float*)(ws + 17432576);
  float* sums           = (float*)(ws + 17563648);
  unsigned short* wcomb = (unsigned short*)(ws + 17567744);

  la_prep<<<dim3(64), dim3(256), 0, stream>>>(w_qkv, wkvb);
  la_fused<<<dim3(NSP / 128, BB), dim3(512), 0, stream>>>(x, wkvb, ctxp, sumsp);
  la_reduce<<<dim3(132), dim3(256), 0, stream>>>(ctxp, sumsp, ctxu, sums);
  la_mid<<<dim3(256, BB), dim3(256), 0, stream>>>(w_out, ctxu, sums, w_qkv, wcomb);
  la_out<<<dim3(NSP / 128, BB), dim3(512), 0, stream>>>(wcomb, x, b_out, out);
}